// Round 1
// baseline (959.304 us; speedup 1.0000x reference)
//
#include <hip/hip_runtime.h>
#include <hip/hip_bf16.h>
#include <stdint.h>

#define Bdim 4
#define Sdim 2048
#define Edim 2048
#define Hdim 16
#define Ddim 128

typedef unsigned short u16;
typedef __attribute__((ext_vector_type(8))) short bf16x8;
typedef __attribute__((ext_vector_type(4))) float f32x4;
typedef __attribute__((ext_vector_type(4))) unsigned short u16x4;

__device__ inline u16 f2bf(float f) {
  union { float f; uint32_t u; } v; v.f = f;
  uint32_t u = v.u;
  return (u16)((u + 0x7FFFu + ((u >> 16) & 1u)) >> 16);
}

__device__ inline f32x4 mfma_bf16(bf16x8 a, bf16x8 b, f32x4 c) {
  return __builtin_amdgcn_mfma_f32_16x16x32_bf16(a, b, c, 0, 0, 0);
}

// async global->LDS, 16B per lane; lds dest = wave-uniform base + lane*16
__device__ inline void load_lds16(const void* g, const void* l) {
  __builtin_amdgcn_global_load_lds(
      (__attribute__((address_space(1))) void*)(uintptr_t)g,
      (__attribute__((address_space(3))) void*)(uint32_t)(uintptr_t)l,
      16, 0, 0);
}

__global__ void cvt_kernel(const float* __restrict__ src, u16* __restrict__ dst, int n4) {
  int i = blockIdx.x * blockDim.x + threadIdx.x;
  if (i < n4) {
    float4 f = ((const float4*)src)[i];
    u16x4 o = { f2bf(f.x), f2bf(f.y), f2bf(f.z), f2bf(f.w) };
    ((u16x4*)dst)[i] = o;
  }
}

// C[m][n] = sum_k A[m][k] * Bw[n][k]   (A:[M][K], Bw:[N][K], bf16 in/out)
// TRANSV: store into Vt[(b*H+h)][d][s] instead of C[m][n]
template <bool TRANSV>
__global__ __launch_bounds__(256)
void gemm_nt(const u16* __restrict__ A, const u16* __restrict__ Bw,
             u16* __restrict__ C, int M, int N, int K) {
  __shared__ u16 As[128][32];
  __shared__ u16 Bs[128][32];
  const int tid = threadIdx.x;
  const int lane = tid & 63;
  const int w = tid >> 6;
  const int wr = w >> 1, wc = w & 1;
  const int bm = blockIdx.x, bn = blockIdx.y;

  const u16* Ag = A + (size_t)(bm * 128 + w * 32 + (lane >> 2)) * K + (lane & 3) * 8;
  const u16* Bg = Bw + (size_t)(bn * 128 + w * 32 + (lane >> 2)) * K + (lane & 3) * 8;
  char* asB = (char*)As + w * 2048;
  char* bsB = (char*)Bs + w * 2048;

  f32x4 acc[4][4];
#pragma unroll
  for (int m = 0; m < 4; ++m)
#pragma unroll
    for (int n = 0; n < 4; ++n)
      acc[m][n] = (f32x4){0.f, 0.f, 0.f, 0.f};

  const char* aRow = (const char*)As + (wr * 64 + (lane & 15)) * 64 + (lane >> 4) * 16;
  const char* bRow = (const char*)Bs + (wc * 64 + (lane & 15)) * 64 + (lane >> 4) * 16;

  for (int k0 = 0; k0 < K; k0 += 32) {
    __syncthreads();
    load_lds16(Ag + k0, asB);
    load_lds16(Ag + k0 + (size_t)16 * K, asB + 1024);
    load_lds16(Bg + k0, bsB);
    load_lds16(Bg + k0 + (size_t)16 * K, bsB + 1024);
    __syncthreads();
    bf16x8 a[4], b[4];
#pragma unroll
    for (int m = 0; m < 4; ++m) a[m] = *(const bf16x8*)(aRow + m * 1024);
#pragma unroll
    for (int n = 0; n < 4; ++n) b[n] = *(const bf16x8*)(bRow + n * 1024);
#pragma unroll
    for (int m = 0; m < 4; ++m)
#pragma unroll
      for (int n = 0; n < 4; ++n)
        acc[m][n] = mfma_bf16(a[m], b[n], acc[m][n]);
  }

  const int r0 = bm * 128 + wr * 64 + ((lane >> 4) << 2);
  const int c0 = bn * 128 + wc * 64 + (lane & 15);
  if (!TRANSV) {
#pragma unroll
    for (int m = 0; m < 4; ++m)
#pragma unroll
      for (int n = 0; n < 4; ++n) {
        int r = r0 + m * 16;
        int c = c0 + n * 16;
#pragma unroll
        for (int j = 0; j < 4; ++j)
          C[(size_t)(r + j) * N + c] = f2bf(acc[m][n][j]);
      }
  } else {
#pragma unroll
    for (int m = 0; m < 4; ++m)
#pragma unroll
      for (int n = 0; n < 4; ++n) {
        int ng = c0 + n * 16;
        int h = ng >> 7, d = ng & 127;
        int mg = r0 + m * 16;
        int b = mg >> 11, s = mg & 2047;
        u16x4 pk = { f2bf(acc[m][n][0]), f2bf(acc[m][n][1]),
                     f2bf(acc[m][n][2]), f2bf(acc[m][n][3]) };
        *(u16x4*)(C + ((size_t)((b * Hdim + h) * Ddim + d)) * Sdim + s) = pk;
      }
  }
}

// causal flash attention; 1 wave per block, 32 q rows per wave, kv tiles of 32
// Q,K: [B*S][E] bf16 (head h at cols h*128..); Vt: [B*H][128][S] bf16; O: [B][H][S][128] f32
__global__ __launch_bounds__(64)
void attn_kernel(const u16* __restrict__ Q, const u16* __restrict__ K,
                 const u16* __restrict__ Vt, float* __restrict__ O) {
  const int lane = threadIdx.x;
  const int qt = blockIdx.x & 63;   // S/32 = 64
  const int bh = blockIdx.x >> 6;
  const int b = bh >> 4, h = bh & 15;
  const int q0 = qt * 32;

  const u16* Qb = Q + (size_t)b * Sdim * Edim + h * Ddim;
  const u16* Kb = K + (size_t)b * Sdim * Edim + h * Ddim;
  const u16* Vb = Vt + (size_t)bh * Ddim * Sdim;

  __shared__ u16 Pl[2][16][32];

  bf16x8 qf[2][4];
#pragma unroll
  for (int rf = 0; rf < 2; ++rf)
#pragma unroll
    for (int c = 0; c < 4; ++c)
      qf[rf][c] = *(const bf16x8*)(Qb + (size_t)(q0 + rf * 16 + (lane & 15)) * Edim +
                                   c * 32 + (lane >> 4) * 8);

  f32x4 oacc[2][8];
#pragma unroll
  for (int rf = 0; rf < 2; ++rf)
#pragma unroll
    for (int f = 0; f < 8; ++f) oacc[rf][f] = (f32x4){0.f, 0.f, 0.f, 0.f};

  float mrow[2][4], lsum[2][4];
#pragma unroll
  for (int rf = 0; rf < 2; ++rf)
#pragma unroll
    for (int r = 0; r < 4; ++r) { mrow[rf][r] = -1e30f; lsum[rf][r] = 0.f; }

  const float scale = 0.08838834764831845f;  // 1/sqrt(128)
  const int ntiles = qt + 1;
  for (int t = 0; t < ntiles; ++t) {
    const int kv0 = t * 32;
    f32x4 sc[2][2];
#pragma unroll
    for (int rf = 0; rf < 2; ++rf)
#pragma unroll
      for (int hh = 0; hh < 2; ++hh) sc[rf][hh] = (f32x4){0.f, 0.f, 0.f, 0.f};

#pragma unroll
    for (int c = 0; c < 4; ++c) {
#pragma unroll
      for (int hh = 0; hh < 2; ++hh) {
        bf16x8 kf = *(const bf16x8*)(Kb + (size_t)(kv0 + hh * 16 + (lane & 15)) * Edim +
                                     c * 32 + (lane >> 4) * 8);
        sc[0][hh] = mfma_bf16(qf[0][c], kf, sc[0][hh]);
        sc[1][hh] = mfma_bf16(qf[1][c], kf, sc[1][hh]);
      }
    }

#pragma unroll
    for (int rf = 0; rf < 2; ++rf) {
      float p0[4], p1[4], mt[4];
      const int cbase = kv0 + (lane & 15);
#pragma unroll
      for (int r = 0; r < 4; ++r) {
        int row = q0 + rf * 16 + ((lane >> 4) << 2) + r;
        float s0 = (cbase <= row) ? sc[rf][0][r] * scale : -1e30f;
        float s1 = (cbase + 16 <= row) ? sc[rf][1][r] * scale : -1e30f;
        p0[r] = s0; p1[r] = s1; mt[r] = fmaxf(s0, s1);
      }
#pragma unroll
      for (int r = 0; r < 4; ++r) {
#pragma unroll
        for (int x = 1; x < 16; x <<= 1)
          mt[r] = fmaxf(mt[r], __shfl_xor(mt[r], x));
      }
      float rs[4];
#pragma unroll
      for (int r = 0; r < 4; ++r) {
        float mnew = fmaxf(mrow[rf][r], mt[r]);
        float corr = __expf(mrow[rf][r] - mnew);
        mrow[rf][r] = mnew;
        p0[r] = __expf(p0[r] - mnew);
        p1[r] = __expf(p1[r] - mnew);
        rs[r] = p0[r] + p1[r];
        lsum[rf][r] *= corr;
#pragma unroll
        for (int f = 0; f < 8; ++f) oacc[rf][f][r] *= corr;
      }
#pragma unroll
      for (int r = 0; r < 4; ++r) {
#pragma unroll
        for (int x = 1; x < 16; x <<= 1)
          rs[r] += __shfl_xor(rs[r], x);
        lsum[rf][r] += rs[r];
      }
#pragma unroll
      for (int r = 0; r < 4; ++r) {
        int i = ((lane >> 4) << 2) + r;
        Pl[rf][i][lane & 15] = f2bf(p0[r]);
        Pl[rf][i][16 + (lane & 15)] = f2bf(p1[r]);
      }
    }
    __syncthreads();
    bf16x8 pa0 = *(const bf16x8*)((const char*)&Pl[0][0][0] + (lane & 15) * 64 + (lane >> 4) * 16);
    bf16x8 pa1 = *(const bf16x8*)((const char*)&Pl[1][0][0] + (lane & 15) * 64 + (lane >> 4) * 16);
    __syncthreads();
#pragma unroll
    for (int f = 0; f < 8; ++f) {
      bf16x8 vf = *(const bf16x8*)(Vb + (size_t)(f * 16 + (lane & 15)) * Sdim +
                                   kv0 + (lane >> 4) * 8);
      oacc[0][f] = mfma_bf16(pa0, vf, oacc[0][f]);
      oacc[1][f] = mfma_bf16(pa1, vf, oacc[1][f]);
    }
  }

  float* Ob = O + ((size_t)bh * Sdim + q0) * Ddim;
#pragma unroll
  for (int rf = 0; rf < 2; ++rf)
#pragma unroll
    for (int f = 0; f < 8; ++f)
#pragma unroll
      for (int r = 0; r < 4; ++r) {
        int i = rf * 16 + ((lane >> 4) << 2) + r;
        Ob[(size_t)i * Ddim + f * 16 + (lane & 15)] = oacc[rf][f][r] / lsum[rf][r];
      }
}

extern "C" void kernel_launch(void* const* d_in, const int* in_sizes, int n_in,
                              void* d_out, int out_size, void* d_ws, size_t ws_size,
                              hipStream_t stream) {
  const float* x  = (const float*)d_in[0];
  const float* Wq = (const float*)d_in[1];
  const float* Wk = (const float*)d_in[2];
  const float* Wv = (const float*)d_in[3];
  float* out = (float*)d_out;
  char* ws = (char*)d_ws;

  // workspace layout (bytes)
  u16* xb  = (u16*)(ws);                    // 32 MiB  [B*S][E]
  u16* wqb = (u16*)(ws + 33554432ull);      //  8 MiB  [E][E]
  u16* wkb = (u16*)(ws + 41943040ull);
  u16* wvb = (u16*)(ws + 50331648ull);
  u16* Qb  = (u16*)(ws + 58720256ull);      // 32 MiB
  u16* Kb  = (u16*)(ws + 92274688ull);      // 32 MiB
  u16* Vt  = (u16*)(ws + 125829120ull);     // 32 MiB  [B*H][128][S]

  const int nX = Bdim * Sdim * Edim;   // 16777216
  const int nW = Edim * Edim;          // 4194304
  cvt_kernel<<<(nX / 4 + 255) / 256, 256, 0, stream>>>(x, xb, nX / 4);
  cvt_kernel<<<(nW / 4 + 255) / 256, 256, 0, stream>>>(Wq, wqb, nW / 4);
  cvt_kernel<<<(nW / 4 + 255) / 256, 256, 0, stream>>>(Wk, wkb, nW / 4);
  cvt_kernel<<<(nW / 4 + 255) / 256, 256, 0, stream>>>(Wv, wvb, nW / 4);

  dim3 g(Bdim * Sdim / 128, Edim / 128);  // (64, 16)
  gemm_nt<false><<<g, 256, 0, stream>>>(xb, wqb, Qb, Bdim * Sdim, Edim, Edim);
  gemm_nt<false><<<g, 256, 0, stream>>>(xb, wkb, Kb, Bdim * Sdim, Edim, Edim);
  gemm_nt<true ><<<g, 256, 0, stream>>>(xb, wvb, Vt, Bdim * Sdim, Edim, Edim);

  attn_kernel<<<Bdim * Hdim * (Sdim / 32), 64, 0, stream>>>(Qb, Kb, Vt, out);
}

// Round 2
// 668.133 us; speedup vs baseline: 1.4358x; 1.4358x over previous
//
#include <hip/hip_runtime.h>
#include <hip/hip_bf16.h>
#include <stdint.h>

#define Bdim 4
#define Sdim 2048
#define Edim 2048
#define Hdim 16
#define Ddim 128

typedef unsigned short u16;
typedef unsigned int u32;
typedef __attribute__((ext_vector_type(8))) short bf16x8;
typedef __attribute__((ext_vector_type(4))) float f32x4;
typedef __attribute__((ext_vector_type(16))) float f32x16;
typedef __attribute__((ext_vector_type(4))) unsigned short u16x4;

__device__ inline u16 f2bf(float f) {
  union { float f; uint32_t u; } v; v.f = f;
  uint32_t u = v.u;
  return (u16)((u + 0x7FFFu + ((u >> 16) & 1u)) >> 16);
}

__device__ inline u32 pkbf(float lo, float hi) {
  float2 t; t.x = lo; t.y = hi;
  union { __hip_bfloat162 h2; u32 u; } cv;
  cv.h2 = __float22bfloat162_rn(t);
  return cv.u;
}

__device__ inline f32x4 mfma16(bf16x8 a, bf16x8 b, f32x4 c) {
  return __builtin_amdgcn_mfma_f32_16x16x32_bf16(a, b, c, 0, 0, 0);
}
__device__ inline f32x16 mfma32(bf16x8 a, bf16x8 b, f32x16 c) {
  return __builtin_amdgcn_mfma_f32_32x32x16_bf16(a, b, c, 0, 0, 0);
}

// async global->LDS, 16B per lane; lds dest = wave-uniform base + lane*16
__device__ inline void load_lds16(const void* g, const void* l) {
  __builtin_amdgcn_global_load_lds(
      (__attribute__((address_space(1))) void*)(uintptr_t)g,
      (__attribute__((address_space(3))) void*)(uint32_t)(uintptr_t)l,
      16, 0, 0);
}

__global__ void cvt_kernel(const float* __restrict__ src, u16* __restrict__ dst, int n4) {
  int i = blockIdx.x * blockDim.x + threadIdx.x;
  if (i < n4) {
    float4 f = ((const float4*)src)[i];
    u16x4 o = { f2bf(f.x), f2bf(f.y), f2bf(f.z), f2bf(f.w) };
    ((u16x4*)dst)[i] = o;
  }
}

// C[m][n] = sum_k A[m][k] * Bw[n][k]   (A:[M][K], Bw:[N][K], bf16 in/out)
// TRANSV: store into Vt[(b*H+h)][d][s] instead of C[m][n]
template <bool TRANSV>
__global__ __launch_bounds__(256)
void gemm_nt(const u16* __restrict__ A, const u16* __restrict__ Bw,
             u16* __restrict__ C, int M, int N, int K) {
  __shared__ u16 As[128][32];
  __shared__ u16 Bs[128][32];
  const int tid = threadIdx.x;
  const int lane = tid & 63;
  const int w = tid >> 6;
  const int wr = w >> 1, wc = w & 1;
  const int bm = blockIdx.x, bn = blockIdx.y;

  const u16* Ag = A + (size_t)(bm * 128 + w * 32 + (lane >> 2)) * K + (lane & 3) * 8;
  const u16* Bg = Bw + (size_t)(bn * 128 + w * 32 + (lane >> 2)) * K + (lane & 3) * 8;
  char* asB = (char*)As + w * 2048;
  char* bsB = (char*)Bs + w * 2048;

  f32x4 acc[4][4];
#pragma unroll
  for (int m = 0; m < 4; ++m)
#pragma unroll
    for (int n = 0; n < 4; ++n)
      acc[m][n] = (f32x4){0.f, 0.f, 0.f, 0.f};

  const char* aRow = (const char*)As + (wr * 64 + (lane & 15)) * 64 + (lane >> 4) * 16;
  const char* bRow = (const char*)Bs + (wc * 64 + (lane & 15)) * 64 + (lane >> 4) * 16;

  for (int k0 = 0; k0 < K; k0 += 32) {
    __syncthreads();
    load_lds16(Ag + k0, asB);
    load_lds16(Ag + k0 + (size_t)16 * K, asB + 1024);
    load_lds16(Bg + k0, bsB);
    load_lds16(Bg + k0 + (size_t)16 * K, bsB + 1024);
    __syncthreads();
    bf16x8 a[4], b[4];
#pragma unroll
    for (int m = 0; m < 4; ++m) a[m] = *(const bf16x8*)(aRow + m * 1024);
#pragma unroll
    for (int n = 0; n < 4; ++n) b[n] = *(const bf16x8*)(bRow + n * 1024);
#pragma unroll
    for (int m = 0; m < 4; ++m)
#pragma unroll
      for (int n = 0; n < 4; ++n)
        acc[m][n] = mfma16(a[m], b[n], acc[m][n]);
  }

  const int r0 = bm * 128 + wr * 64 + ((lane >> 4) << 2);
  const int c0 = bn * 128 + wc * 64 + (lane & 15);
  if (!TRANSV) {
#pragma unroll
    for (int m = 0; m < 4; ++m)
#pragma unroll
      for (int n = 0; n < 4; ++n) {
        int r = r0 + m * 16;
        int c = c0 + n * 16;
#pragma unroll
        for (int j = 0; j < 4; ++j)
          C[(size_t)(r + j) * N + c] = f2bf(acc[m][n][j]);
      }
  } else {
#pragma unroll
    for (int m = 0; m < 4; ++m)
#pragma unroll
      for (int n = 0; n < 4; ++n) {
        int ng = c0 + n * 16;
        int h = ng >> 7, d = ng & 127;
        int mg = r0 + m * 16;
        int b = mg >> 11, s = mg & 2047;
        u16x4 pk = { f2bf(acc[m][n][0]), f2bf(acc[m][n][1]),
                     f2bf(acc[m][n][2]), f2bf(acc[m][n][3]) };
        *(u16x4*)(C + ((size_t)((b * Hdim + h) * Ddim + d)) * Sdim + s) = pk;
      }
  }
}

// Causal flash attention, swapped-operand 32x32 MFMA, no LDS, no barriers.
// 4 independent waves/block, each wave owns 32 q rows; KV tile = 64.
// Q,K: [B*S][E] bf16 (head h at cols h*128..); Vt: [B*H][128][S] bf16;
// O: [B][H][S][128] f32.
// Swapped QK^T: sc = mfma(K, Q) -> lane l holds scores of q-row (l&31),
//   kv(reg r, subtile t) = 64*tile + 32*t + (r&3) + 8*(r>>2) + 4*(l>>5).
// Swapped PV: o = mfma(Vt, P) -> lane l holds O[q=l&31][d in regs]; all
//   softmax state (m, lsum, rescale) is per-lane scalar.
__global__ __launch_bounds__(256)
void attn_kernel(const u16* __restrict__ Q, const u16* __restrict__ K,
                 const u16* __restrict__ Vt, float* __restrict__ O) {
  const int tid = threadIdx.x;
  const int lane = tid & 63;
  const int w = tid >> 6;
  const int l31 = lane & 31;
  const int hi = lane >> 5;

  const int bid = blockIdx.x;
  const int bh = bid & 63;              // head index b*16+h
  const int qg = 15 - (bid >> 6);       // longest q-groups dispatch first
  const int qt = qg * 4 + w;            // 0..63, this wave's q-tile of 32
  const int qw0 = qt * 32;
  const int b = bh >> 4, h = bh & 15;

  const u16* Qb = Q + (size_t)b * Sdim * Edim + h * Ddim;
  const u16* Kb = K + (size_t)b * Sdim * Edim + h * Ddim;
  const u16* Vb = Vt + (size_t)bh * Ddim * Sdim;

  // Q fragments (B-operand): lane: q row = qw0+l31, k = c*16 + hi*8 + e
  bf16x8 qf[8];
  {
    const u16* qrow = Qb + (size_t)(qw0 + l31) * Edim + hi * 8;
#pragma unroll
    for (int c = 0; c < 8; ++c) qf[c] = *(const bf16x8*)(qrow + c * 16);
  }

  f32x16 oacc[4];
#pragma unroll
  for (int d = 0; d < 4; ++d)
#pragma unroll
    for (int i = 0; i < 16; ++i) oacc[d][i] = 0.f;

  float m2 = -1e30f, lsum = 0.f;
  const float K1SC = 0.08838834764831845f * 1.4426950408889634f;  // 1/sqrt(128)*log2e
  const int qrel = qw0 + l31;

  const u16* kcur = Kb + (size_t)l31 * Edim + hi * 8;
  const u16* vcur = Vb + (size_t)l31 * Sdim + hi * 8;

  const int ntiles = (qw0 + 31) / 64 + 1;
  for (int t = 0; t < ntiles; ++t) {
    const int kv0 = t * 64;

    // ---- QK^T (swapped): 16 MFMAs, K fragments direct from global ----
    f32x16 sc0, sc1;
#pragma unroll
    for (int i = 0; i < 16; ++i) { sc0[i] = 0.f; sc1[i] = 0.f; }
    {
      const u16* kp1 = kcur + (size_t)32 * Edim;
#pragma unroll
      for (int c = 0; c < 8; ++c) {
        bf16x8 kf0 = *(const bf16x8*)(kcur + c * 16);
        bf16x8 kf1 = *(const bf16x8*)(kp1 + c * 16);
        sc0 = mfma32(kf0, qf[c], sc0);
        sc1 = mfma32(kf1, qf[c], sc1);
      }
    }

    // ---- scale + causal mask + row max (in-register, one shfl) ----
    float psc[32];
    float ma = -1e30f, mb = -1e30f, mc = -1e30f, md = -1e30f;
    if (kv0 + 63 > qw0) {  // diagonal tile: apply mask
#pragma unroll
      for (int r = 0; r < 16; ++r) {
        const int cr = (r & 3) + 8 * (r >> 2) + 4 * hi;
        float v0 = (kv0 + cr <= qrel) ? sc0[r] * K1SC : -1e30f;
        float v1 = (kv0 + 32 + cr <= qrel) ? sc1[r] * K1SC : -1e30f;
        psc[r] = v0; psc[16 + r] = v1;
        if ((r & 3) == 0) { ma = fmaxf(ma, fmaxf(v0, v1)); }
        else if ((r & 3) == 1) { mb = fmaxf(mb, fmaxf(v0, v1)); }
        else if ((r & 3) == 2) { mc = fmaxf(mc, fmaxf(v0, v1)); }
        else { md = fmaxf(md, fmaxf(v0, v1)); }
      }
    } else {
#pragma unroll
      for (int r = 0; r < 16; ++r) {
        float v0 = sc0[r] * K1SC;
        float v1 = sc1[r] * K1SC;
        psc[r] = v0; psc[16 + r] = v1;
        if ((r & 3) == 0) { ma = fmaxf(ma, fmaxf(v0, v1)); }
        else if ((r & 3) == 1) { mb = fmaxf(mb, fmaxf(v0, v1)); }
        else if ((r & 3) == 2) { mc = fmaxf(mc, fmaxf(v0, v1)); }
        else { md = fmaxf(md, fmaxf(v0, v1)); }
      }
    }
    float mt = fmaxf(fmaxf(ma, mb), fmaxf(mc, md));
    float mo = fmaxf(mt, __shfl_xor(mt, 32));

    // ---- defer-max rescale (T13, THR=8 in log2 units) ----
    if (__any(mo - m2 > 8.0f)) {
      float mnew = fmaxf(m2, mo);
      float corr = __builtin_amdgcn_exp2f(m2 - mnew);
      m2 = mnew;
      lsum *= corr;
#pragma unroll
      for (int d = 0; d < 4; ++d)
#pragma unroll
        for (int i = 0; i < 16; ++i) oacc[d][i] *= corr;
    }

    // ---- exp + row sum ----
    float rs0 = 0.f, rs1 = 0.f, rs2 = 0.f, rs3 = 0.f;
#pragma unroll
    for (int r = 0; r < 32; r += 4) {
      psc[r]     = __builtin_amdgcn_exp2f(psc[r] - m2);     rs0 += psc[r];
      psc[r + 1] = __builtin_amdgcn_exp2f(psc[r + 1] - m2); rs1 += psc[r + 1];
      psc[r + 2] = __builtin_amdgcn_exp2f(psc[r + 2] - m2); rs2 += psc[r + 2];
      psc[r + 3] = __builtin_amdgcn_exp2f(psc[r + 3] - m2); rs3 += psc[r + 3];
    }
    float rs = (rs0 + rs1) + (rs2 + rs3);
    rs += __shfl_xor(rs, 32);
    lsum += rs;

    // ---- P -> bf16 fragments (pack + half-swap redistribution) ----
    u32 pk[16], sx[16];
#pragma unroll
    for (int i = 0; i < 16; ++i) pk[i] = pkbf(psc[2 * i], psc[2 * i + 1]);
#pragma unroll
    for (int i = 0; i < 16; ++i) sx[i] = __shfl_xor(pk[i], 32);
    bf16x8 pa[4];
#pragma unroll
    for (int t2 = 0; t2 < 2; ++t2)
#pragma unroll
      for (int q2 = 0; q2 < 2; ++q2) {
        const int base = t2 * 8 + q2 * 4;
        union { u32 w[4]; bf16x8 v; } cv;
        cv.w[0] = hi ? sx[base + 2] : pk[base + 0];
        cv.w[1] = hi ? sx[base + 3] : pk[base + 1];
        cv.w[2] = hi ? pk[base + 2] : sx[base + 0];
        cv.w[3] = hi ? pk[base + 3] : sx[base + 1];
        pa[t2 * 2 + q2] = cv.v;
      }

    // ---- PV (swapped): 16 MFMAs, Vt fragments direct from global ----
#pragma unroll
    for (int dblk = 0; dblk < 4; ++dblk) {
      const u16* vpp = vcur + (size_t)dblk * 32 * Sdim;
#pragma unroll
      for (int ks = 0; ks < 4; ++ks) {
        bf16x8 vf = *(const bf16x8*)(vpp + ks * 16);
        oacc[dblk] = mfma32(vf, pa[ks], oacc[dblk]);
      }
    }

    kcur += (size_t)64 * Edim;
    vcur += 64;
  }

  // ---- epilogue: divide by lsum, store f32x4 runs ----
  float inv = 1.0f / lsum;
  float* Ob = O + ((size_t)bh * Sdim + qw0 + l31) * Ddim + hi * 4;
#pragma unroll
  for (int dblk = 0; dblk < 4; ++dblk)
#pragma unroll
    for (int g = 0; g < 4; ++g) {
      f32x4 o4 = { oacc[dblk][4 * g] * inv, oacc[dblk][4 * g + 1] * inv,
                   oacc[dblk][4 * g + 2] * inv, oacc[dblk][4 * g + 3] * inv };
      *(f32x4*)(Ob + dblk * 32 + g * 8) = o4;
    }
}

extern "C" void kernel_launch(void* const* d_in, const int* in_sizes, int n_in,
                              void* d_out, int out_size, void* d_ws, size_t ws_size,
                              hipStream_t stream) {
  const float* x  = (const float*)d_in[0];
  const float* Wq = (const float*)d_in[1];
  const float* Wk = (const float*)d_in[2];
  const float* Wv = (const float*)d_in[3];
  float* out = (float*)d_out;
  char* ws = (char*)d_ws;

  // workspace layout (bytes)
  u16* xb  = (u16*)(ws);                    // 32 MiB  [B*S][E]
  u16* wqb = (u16*)(ws + 33554432ull);      //  8 MiB  [E][E]
  u16* wkb = (u16*)(ws + 41943040ull);
  u16* wvb = (u16*)(ws + 50331648ull);
  u16* Qb  = (u16*)(ws + 58720256ull);      // 32 MiB
  u16* Kb  = (u16*)(ws + 92274688ull);      // 32 MiB
  u16* Vt  = (u16*)(ws + 125829120ull);     // 32 MiB  [B*H][128][S]

  const int nX = Bdim * Sdim * Edim;   // 16777216
  const int nW = Edim * Edim;          // 4194304
  cvt_kernel<<<(nX / 4 + 255) / 256, 256, 0, stream>>>(x, xb, nX / 4);
  cvt_kernel<<<(nW / 4 + 255) / 256, 256, 0, stream>>>(Wq, wqb, nW / 4);
  cvt_kernel<<<(nW / 4 + 255) / 256, 256, 0, stream>>>(Wk, wkb, nW / 4);
  cvt_kernel<<<(nW / 4 + 255) / 256, 256, 0, stream>>>(Wv, wvb, nW / 4);

  dim3 g(Bdim * Sdim / 128, Edim / 128);  // (64, 16)
  gemm_nt<false><<<g, 256, 0, stream>>>(xb, wqb, Qb, Bdim * Sdim, Edim, Edim);
  gemm_nt<false><<<g, 256, 0, stream>>>(xb, wkb, Kb, Bdim * Sdim, Edim, Edim);
  gemm_nt<true ><<<g, 256, 0, stream>>>(xb, wvb, Vt, Bdim * Sdim, Edim, Edim);

  attn_kernel<<<Bdim * Hdim * (Sdim / 32) / 4, 256, 0, stream>>>(Qb, Kb, Vt, out);
}

// Round 3
// 506.311 us; speedup vs baseline: 1.8947x; 1.3196x over previous
//
#include <hip/hip_runtime.h>
#include <hip/hip_bf16.h>
#include <stdint.h>

#define Bdim 4
#define Sdim 2048
#define Edim 2048
#define Hdim 16
#define Ddim 128

typedef unsigned short u16;
typedef unsigned int u32;
typedef __attribute__((ext_vector_type(8))) short bf16x8;
typedef __attribute__((ext_vector_type(4))) float f32x4;
typedef __attribute__((ext_vector_type(16))) float f32x16;
typedef __attribute__((ext_vector_type(4))) unsigned short u16x4;

__device__ inline u16 f2bf(float f) {
  union { float f; uint32_t u; } v; v.f = f;
  uint32_t u = v.u;
  return (u16)((u + 0x7FFFu + ((u >> 16) & 1u)) >> 16);
}

__device__ inline u32 pkbf(float lo, float hi) {
  float2 t; t.x = lo; t.y = hi;
  union { __hip_bfloat162 h2; u32 u; } cv;
  cv.h2 = __float22bfloat162_rn(t);
  return cv.u;
}

__device__ inline f32x4 mfma16(bf16x8 a, bf16x8 b, f32x4 c) {
  return __builtin_amdgcn_mfma_f32_16x16x32_bf16(a, b, c, 0, 0, 0);
}
__device__ inline f32x16 mfma32(bf16x8 a, bf16x8 b, f32x16 c) {
  return __builtin_amdgcn_mfma_f32_32x32x16_bf16(a, b, c, 0, 0, 0);
}

// async global->LDS, 16B per lane; lds dest = wave-uniform base + lane*16
__device__ inline void load_lds16(const void* g, const void* l) {
  __builtin_amdgcn_global_load_lds(
      (__attribute__((address_space(1))) void*)(uintptr_t)g,
      (__attribute__((address_space(3))) void*)(uint32_t)(uintptr_t)l,
      16, 0, 0);
}

__global__ void cvt_kernel(const float* __restrict__ src, u16* __restrict__ dst, int n4) {
  int i = blockIdx.x * blockDim.x + threadIdx.x;
  if (i < n4) {
    float4 f = ((const float4*)src)[i];
    u16x4 o = { f2bf(f.x), f2bf(f.y), f2bf(f.z), f2bf(f.w) };
    ((u16x4*)dst)[i] = o;
  }
}

// C[m][n] = sum_k A[m][k] * Bw[n][k]   (A:[M][K], Bw:[N][K], bf16 in/out)
// TRANSV: store into Vt[(b*H+h)][d][s] instead of C[m][n]
template <bool TRANSV>
__global__ __launch_bounds__(256)
void gemm_nt(const u16* __restrict__ A, const u16* __restrict__ Bw,
             u16* __restrict__ C, int M, int N, int K) {
  __shared__ u16 As[128][32];
  __shared__ u16 Bs[128][32];
  const int tid = threadIdx.x;
  const int lane = tid & 63;
  const int w = tid >> 6;
  const int wr = w >> 1, wc = w & 1;
  const int bm = blockIdx.x, bn = blockIdx.y;

  const u16* Ag = A + (size_t)(bm * 128 + w * 32 + (lane >> 2)) * K + (lane & 3) * 8;
  const u16* Bg = Bw + (size_t)(bn * 128 + w * 32 + (lane >> 2)) * K + (lane & 3) * 8;
  char* asB = (char*)As + w * 2048;
  char* bsB = (char*)Bs + w * 2048;

  f32x4 acc[4][4];
#pragma unroll
  for (int m = 0; m < 4; ++m)
#pragma unroll
    for (int n = 0; n < 4; ++n)
      acc[m][n] = (f32x4){0.f, 0.f, 0.f, 0.f};

  const char* aRow = (const char*)As + (wr * 64 + (lane & 15)) * 64 + (lane >> 4) * 16;
  const char* bRow = (const char*)Bs + (wc * 64 + (lane & 15)) * 64 + (lane >> 4) * 16;

  for (int k0 = 0; k0 < K; k0 += 32) {
    __syncthreads();
    load_lds16(Ag + k0, asB);
    load_lds16(Ag + k0 + (size_t)16 * K, asB + 1024);
    load_lds16(Bg + k0, bsB);
    load_lds16(Bg + k0 + (size_t)16 * K, bsB + 1024);
    __syncthreads();
    bf16x8 a[4], b[4];
#pragma unroll
    for (int m = 0; m < 4; ++m) a[m] = *(const bf16x8*)(aRow + m * 1024);
#pragma unroll
    for (int n = 0; n < 4; ++n) b[n] = *(const bf16x8*)(bRow + n * 1024);
#pragma unroll
    for (int m = 0; m < 4; ++m)
#pragma unroll
      for (int n = 0; n < 4; ++n)
        acc[m][n] = mfma16(a[m], b[n], acc[m][n]);
  }

  const int r0 = bm * 128 + wr * 64 + ((lane >> 4) << 2);
  const int c0 = bn * 128 + wc * 64 + (lane & 15);
  if (!TRANSV) {
#pragma unroll
    for (int m = 0; m < 4; ++m)
#pragma unroll
      for (int n = 0; n < 4; ++n) {
        int r = r0 + m * 16;
        int c = c0 + n * 16;
#pragma unroll
        for (int j = 0; j < 4; ++j)
          C[(size_t)(r + j) * N + c] = f2bf(acc[m][n][j]);
      }
  } else {
#pragma unroll
    for (int m = 0; m < 4; ++m)
#pragma unroll
      for (int n = 0; n < 4; ++n) {
        int ng = c0 + n * 16;
        int h = ng >> 7, d = ng & 127;
        int mg = r0 + m * 16;
        int b = mg >> 11, s = mg & 2047;
        u16x4 pk = { f2bf(acc[m][n][0]), f2bf(acc[m][n][1]),
                     f2bf(acc[m][n][2]), f2bf(acc[m][n][3]) };
        *(u16x4*)(C + ((size_t)((b * Hdim + h) * Ddim + d)) * Sdim + s) = pk;
      }
  }
}

// Causal flash attention, swapped-operand 32x32 MFMA.
// Block = 4 waves sharing one head and a 128-row q-block; each wave owns 32 q
// rows. KV tile = 64, double-buffered in LDS (K swizzled ^row&15, V ^row&7),
// staged via global_load_lds with pre-swizzled global source; 2-phase pipeline
// (stage t+1 issued before compute of t, one __syncthreads per tile).
// Swapped QK^T: sc = mfma(K, Q) -> lane l holds scores of q-row (l&31);
// swapped PV: o = mfma(Vt, P) -> all softmax state per-lane scalar.
__global__ __launch_bounds__(256)
void attn_kernel(const u16* __restrict__ Q, const u16* __restrict__ K,
                 const u16* __restrict__ Vt, float* __restrict__ O) {
  __shared__ u16 Ks[2][64 * 128];
  __shared__ u16 Vs[2][128 * 64];

  const int tid = threadIdx.x;
  const int lane = tid & 63;
  const int w = tid >> 6;
  const int l31 = lane & 31;
  const int hi = lane >> 5;

  const int bid = blockIdx.x;
  const int bh = bid & 63;              // head index b*16+h
  const int qg = 15 - (bid >> 6);       // longest q-groups dispatch first
  const int q0 = qg * 128;
  const int qw0 = q0 + w * 32;          // this wave's 32 q rows
  const int b = bh >> 4, h = bh & 15;

  const u16* Qb = Q + (size_t)b * Sdim * Edim + h * Ddim;
  const u16* Kb = K + (size_t)b * Sdim * Edim + h * Ddim;
  const u16* Vb = Vt + (size_t)bh * Ddim * Sdim;

  // Q fragments (B-operand): lane: q row = qw0+l31, k = c*16 + hi*8 + e
  bf16x8 qf[8];
  {
    const u16* qrow = Qb + (size_t)(qw0 + l31) * Edim + hi * 8;
#pragma unroll
    for (int c = 0; c < 8; ++c) qf[c] = *(const bf16x8*)(qrow + c * 16);
  }

  f32x16 oacc[4];
#pragma unroll
  for (int d = 0; d < 4; ++d)
#pragma unroll
    for (int i = 0; i < 16; ++i) oacc[d][i] = 0.f;

  float m2 = -1e30f, lsum = 0.f;
  const float K1SC = 0.08838834764831845f * 1.4426950408889634f;  // 1/sqrt(128)*log2e
  const int qrel = qw0 + l31;

  const int nt = 2 * qg + 2;                 // block's causal tile count
  const int ntw = (qw0 + 31) / 64 + 1;       // this wave's tile count

  // staging lane constants
  const int krow_off = (lane >> 4);          // K: 4 rows per 1KB issue
  const int kchunk = lane & 15;
  const int vrow_off = (lane >> 3);          // V: 8 rows per 1KB issue
  const int vchunk = lane & 7;

#define STAGE(bufi, tt)                                                        \
  {                                                                            \
    const int kv0s = (tt) * 64;                                                \
    _Pragma("unroll")                                                          \
    for (int i = 0; i < 4; ++i) {                                              \
      const int rbase = w * 16 + i * 4;                                        \
      const int row = rbase + krow_off;                                        \
      const int cs = kchunk ^ (row & 15);                                      \
      load_lds16(Kb + (size_t)(kv0s + row) * Edim + cs * 8,                    \
                 &Ks[bufi][rbase * 128]);                                      \
    }                                                                          \
    _Pragma("unroll")                                                          \
    for (int i = 0; i < 4; ++i) {                                              \
      const int rbase = w * 32 + i * 8;                                        \
      const int row = rbase + vrow_off;                                        \
      const int cs = vchunk ^ (row & 7);                                       \
      load_lds16(Vb + (size_t)row * Sdim + kv0s + cs * 8,                      \
                 &Vs[bufi][rbase * 64]);                                       \
    }                                                                          \
  }

  STAGE(0, 0);
  __syncthreads();

  for (int t = 0; t < nt; ++t) {
    const int cur = t & 1;
    if (t + 1 < nt) STAGE(cur ^ 1, t + 1);

    if (t < ntw) {
      const int kv0 = t * 64;

      // ---- QK^T (swapped): 16 MFMAs, K frags from swizzled LDS ----
      f32x16 sc0, sc1;
#pragma unroll
      for (int i = 0; i < 16; ++i) { sc0[i] = 0.f; sc1[i] = 0.f; }
#pragma unroll
      for (int c = 0; c < 8; ++c) {
        const int ch = c * 2 + hi;
        const int r0r = l31;
        const int r1r = 32 + l31;
        bf16x8 kf0 = *(const bf16x8*)&Ks[cur][r0r * 128 + (ch ^ (r0r & 15)) * 8];
        bf16x8 kf1 = *(const bf16x8*)&Ks[cur][r1r * 128 + (ch ^ (r1r & 15)) * 8];
        sc0 = mfma32(kf0, qf[c], sc0);
        sc1 = mfma32(kf1, qf[c], sc1);
      }

      // ---- scale + causal mask + row max ----
      float psc[32];
      float ma = -1e30f, mb = -1e30f, mc = -1e30f, md = -1e30f;
      if (kv0 + 64 > qw0) {  // diagonal tile: apply mask
#pragma unroll
        for (int r = 0; r < 16; ++r) {
          const int cr = (r & 3) + 8 * (r >> 2) + 4 * hi;
          float v0 = (kv0 + cr <= qrel) ? sc0[r] * K1SC : -1e30f;
          float v1 = (kv0 + 32 + cr <= qrel) ? sc1[r] * K1SC : -1e30f;
          psc[r] = v0; psc[16 + r] = v1;
          if ((r & 3) == 0) { ma = fmaxf(ma, fmaxf(v0, v1)); }
          else if ((r & 3) == 1) { mb = fmaxf(mb, fmaxf(v0, v1)); }
          else if ((r & 3) == 2) { mc = fmaxf(mc, fmaxf(v0, v1)); }
          else { md = fmaxf(md, fmaxf(v0, v1)); }
        }
      } else {
#pragma unroll
        for (int r = 0; r < 16; ++r) {
          float v0 = sc0[r] * K1SC;
          float v1 = sc1[r] * K1SC;
          psc[r] = v0; psc[16 + r] = v1;
          if ((r & 3) == 0) { ma = fmaxf(ma, fmaxf(v0, v1)); }
          else if ((r & 3) == 1) { mb = fmaxf(mb, fmaxf(v0, v1)); }
          else if ((r & 3) == 2) { mc = fmaxf(mc, fmaxf(v0, v1)); }
          else { md = fmaxf(md, fmaxf(v0, v1)); }
        }
      }
      float mt = fmaxf(fmaxf(ma, mb), fmaxf(mc, md));
      float mo = fmaxf(mt, __shfl_xor(mt, 32));

      // ---- defer-max rescale (T13, THR=8 in log2 units) ----
      if (__any(mo - m2 > 8.0f)) {
        float mnew = fmaxf(m2, mo);
        float corr = __builtin_amdgcn_exp2f(m2 - mnew);
        m2 = mnew;
        lsum *= corr;
#pragma unroll
        for (int d = 0; d < 4; ++d)
#pragma unroll
          for (int i = 0; i < 16; ++i) oacc[d][i] *= corr;
      }

      // ---- exp + row sum ----
      float rs0 = 0.f, rs1 = 0.f, rs2 = 0.f, rs3 = 0.f;
#pragma unroll
      for (int r = 0; r < 32; r += 4) {
        psc[r]     = __builtin_amdgcn_exp2f(psc[r] - m2);     rs0 += psc[r];
        psc[r + 1] = __builtin_amdgcn_exp2f(psc[r + 1] - m2); rs1 += psc[r + 1];
        psc[r + 2] = __builtin_amdgcn_exp2f(psc[r + 2] - m2); rs2 += psc[r + 2];
        psc[r + 3] = __builtin_amdgcn_exp2f(psc[r + 3] - m2); rs3 += psc[r + 3];
      }
      float rs = (rs0 + rs1) + (rs2 + rs3);
      rs += __shfl_xor(rs, 32);
      lsum += rs;

      // ---- P -> bf16 fragments (pack + half-swap redistribution) ----
      u32 pk[16], sx[16];
#pragma unroll
      for (int i = 0; i < 16; ++i) pk[i] = pkbf(psc[2 * i], psc[2 * i + 1]);
#pragma unroll
      for (int i = 0; i < 16; ++i) sx[i] = __shfl_xor(pk[i], 32);
      bf16x8 pa[4];
#pragma unroll
      for (int t2 = 0; t2 < 2; ++t2)
#pragma unroll
        for (int q2 = 0; q2 < 2; ++q2) {
          const int base = t2 * 8 + q2 * 4;
          union { u32 w[4]; bf16x8 v; } cv;
          cv.w[0] = hi ? sx[base + 2] : pk[base + 0];
          cv.w[1] = hi ? sx[base + 3] : pk[base + 1];
          cv.w[2] = hi ? pk[base + 2] : sx[base + 0];
          cv.w[3] = hi ? pk[base + 3] : sx[base + 1];
          pa[t2 * 2 + q2] = cv.v;
        }

      // ---- PV (swapped): 16 MFMAs, V frags from swizzled LDS ----
#pragma unroll
      for (int dblk = 0; dblk < 4; ++dblk) {
        const int row = dblk * 32 + l31;
#pragma unroll
        for (int ks = 0; ks < 4; ++ks) {
          const int ch = ks * 2 + hi;
          bf16x8 vf = *(const bf16x8*)&Vs[cur][row * 64 + (ch ^ (row & 7)) * 8];
          oacc[dblk] = mfma32(vf, pa[ks], oacc[dblk]);
        }
      }
    }

    __syncthreads();
  }

  // ---- epilogue: divide by lsum, store f32x4 runs ----
  float inv = 1.0f / lsum;
  float* Ob = O + ((size_t)bh * Sdim + qw0 + l31) * Ddim + hi * 4;
#pragma unroll
  for (int dblk = 0; dblk < 4; ++dblk)
#pragma unroll
    for (int g = 0; g < 4; ++g) {
      f32x4 o4 = { oacc[dblk][4 * g] * inv, oacc[dblk][4 * g + 1] * inv,
                   oacc[dblk][4 * g + 2] * inv, oacc[dblk][4 * g + 3] * inv };
      *(f32x4*)(Ob + dblk * 32 + g * 8) = o4;
    }
}

extern "C" void kernel_launch(void* const* d_in, const int* in_sizes, int n_in,
                              void* d_out, int out_size, void* d_ws, size_t ws_size,
                              hipStream_t stream) {
  const float* x  = (const float*)d_in[0];
  const float* Wq = (const float*)d_in[1];
  const float* Wk = (const float*)d_in[2];
  const float* Wv = (const float*)d_in[3];
  float* out = (float*)d_out;
  char* ws = (char*)d_ws;

  // workspace layout (bytes)
  u16* xb  = (u16*)(ws);                    // 32 MiB  [B*S][E]
  u16* wqb = (u16*)(ws + 33554432ull);      //  8 MiB  [E][E]
  u16* wkb = (u16*)(ws + 41943040ull);
  u16* wvb = (u16*)(ws + 50331648ull);
  u16* Qb  = (u16*)(ws + 58720256ull);      // 32 MiB
  u16* Kb  = (u16*)(ws + 92274688ull);      // 32 MiB
  u16* Vt  = (u16*)(ws + 125829120ull);     // 32 MiB  [B*H][128][S]

  const int nX = Bdim * Sdim * Edim;   // 16777216
  const int nW = Edim * Edim;          // 4194304
  cvt_kernel<<<(nX / 4 + 255) / 256, 256, 0, stream>>>(x, xb, nX / 4);
  cvt_kernel<<<(nW / 4 + 255) / 256, 256, 0, stream>>>(Wq, wqb, nW / 4);
  cvt_kernel<<<(nW / 4 + 255) / 256, 256, 0, stream>>>(Wk, wkb, nW / 4);
  cvt_kernel<<<(nW / 4 + 255) / 256, 256, 0, stream>>>(Wv, wvb, nW / 4);

  dim3 g(Bdim * Sdim / 128, Edim / 128);  // (64, 16)
  gemm_nt<false><<<g, 256, 0, stream>>>(xb, wqb, Qb, Bdim * Sdim, Edim, Edim);
  gemm_nt<false><<<g, 256, 0, stream>>>(xb, wkb, Kb, Bdim * Sdim, Edim, Edim);
  gemm_nt<true ><<<g, 256, 0, stream>>>(xb, wvb, Vt, Bdim * Sdim, Edim, Edim);

  attn_kernel<<<Bdim * Hdim * (Sdim / 128), 256, 0, stream>>>(Qb, Kb, Vt, out);
}

// Round 4
// 392.203 us; speedup vs baseline: 2.4459x; 1.2909x over previous
//
#include <hip/hip_runtime.h>
#include <hip/hip_bf16.h>
#include <stdint.h>

#define Bdim 4
#define Sdim 2048
#define Edim 2048
#define Hdim 16
#define Ddim 128

typedef unsigned short u16;
typedef unsigned int u32;
typedef __attribute__((ext_vector_type(8))) short bf16x8;
typedef __attribute__((ext_vector_type(4))) float f32x4;
typedef __attribute__((ext_vector_type(16))) float f32x16;
typedef __attribute__((ext_vector_type(4))) unsigned short u16x4;

__device__ inline u16 f2bf(float f) {
  union { float f; uint32_t u; } v; v.f = f;
  uint32_t u = v.u;
  return (u16)((u + 0x7FFFu + ((u >> 16) & 1u)) >> 16);
}

__device__ inline u32 pkbf(float lo, float hi) {
  float2 t; t.x = lo; t.y = hi;
  union { __hip_bfloat162 h2; u32 u; } cv;
  cv.h2 = __float22bfloat162_rn(t);
  return cv.u;
}

__device__ inline f32x4 mfma16(bf16x8 a, bf16x8 b, f32x4 c) {
  return __builtin_amdgcn_mfma_f32_16x16x32_bf16(a, b, c, 0, 0, 0);
}
__device__ inline f32x16 mfma32(bf16x8 a, bf16x8 b, f32x16 c) {
  return __builtin_amdgcn_mfma_f32_32x32x16_bf16(a, b, c, 0, 0, 0);
}

// async global->LDS, 16B per lane; lds dest = wave-uniform base + lane*16
__device__ inline void load_lds16(const void* g, const void* l) {
  __builtin_amdgcn_global_load_lds(
      (__attribute__((address_space(1))) void*)(uintptr_t)g,
      (__attribute__((address_space(3))) void*)(uint32_t)(uintptr_t)l,
      16, 0, 0);
}

__global__ void cvt_kernel(const float* __restrict__ src, u16* __restrict__ dst, int n4) {
  int i = blockIdx.x * blockDim.x + threadIdx.x;
  if (i < n4) {
    float4 f = ((const float4*)src)[i];
    u16x4 o = { f2bf(f.x), f2bf(f.y), f2bf(f.z), f2bf(f.w) };
    ((u16x4*)dst)[i] = o;
  }
}

// C[m][n] = sum_k A[m][k] * Bw[n][k]   (A:[M][K], Bw:[N][K], bf16 in/out)
// 256x256 tile, 8 waves (2M x 4N), BK=32, ring of 4 LDS slots, counted vmcnt,
// one raw s_barrier per K-tile. LDS chunk-swizzle: chunk ^= (row+(row>>2))&3.
// TRANSV: store into Vt[(b*H+h)][d][s] instead of C[m][n].
template <bool TRANSV>
__global__ __launch_bounds__(512, 2)
void gemm_nt(const u16* __restrict__ A, const u16* __restrict__ Bw,
             u16* __restrict__ C, int M, int N, int K) {
  __shared__ char lds[131072];  // [4 slots][A 16KB] then [4 slots][B 16KB]

  const int tid = threadIdx.x;
  const int lane = tid & 63;
  const int w = tid >> 6;            // 0..7
  const int wm = w >> 2, wn = w & 3; // 2 x 4 wave grid
  const int bm = blockIdx.x, bn = blockIdx.y;
  const int NT = K >> 5;             // K-tiles of 32

  // staging lane constants (each 1KB issue = 16 rows x 64B)
  const int srow_off = lane >> 2;    // 0..15
  const int schunk = lane & 3;

  // fragment-read lane constants
  const int l15 = lane & 15;
  const int l4 = lane >> 4;          // k-chunk 0..3
  const int rA = wm * 128 + l15;     // A row base within tile (fm adds 16k, g invariant)
  const int rB = wn * 64 + l15;
  const int gA = (rA + (rA >> 2)) & 3;
  const int gB = (rB + (rB >> 2)) & 3;
  const int aoff = rA * 64 + ((l4 ^ gA) << 4);
  const int boff = rB * 64 + ((l4 ^ gB) << 4);

  const u16* Agp = A + (size_t)(bm * 256) * K;
  const u16* Bgp = Bw + (size_t)(bn * 256) * K;

  f32x4 acc[8][4];
#pragma unroll
  for (int m = 0; m < 8; ++m)
#pragma unroll
    for (int n = 0; n < 4; ++n)
      acc[m][n] = (f32x4){0.f, 0.f, 0.f, 0.f};

#define GSTAGE(tt)                                                             \
  {                                                                            \
    const int slot_ = (tt) & 3;                                                \
    char* ab_ = lds + slot_ * 16384;                                           \
    char* bb_ = lds + 65536 + slot_ * 16384;                                   \
    _Pragma("unroll")                                                          \
    for (int i_ = 0; i_ < 2; ++i_) {                                           \
      const int rbase_ = w * 32 + i_ * 16;                                     \
      const int row_ = rbase_ + srow_off;                                      \
      const int src_ = schunk ^ ((row_ + (row_ >> 2)) & 3);                    \
      load_lds16(Agp + (size_t)row_ * K + (tt) * 32 + src_ * 8,                \
                 ab_ + rbase_ * 64);                                           \
      load_lds16(Bgp + (size_t)row_ * K + (tt) * 32 + src_ * 8,                \
                 bb_ + rbase_ * 64);                                           \
    }                                                                          \
  }

  GSTAGE(0);
  GSTAGE(1);
  asm volatile("s_waitcnt vmcnt(4)" ::: "memory");
  __builtin_amdgcn_s_barrier();

  for (int t = 0; t < NT; ++t) {
    if (t + 2 < NT) GSTAGE(t + 2);

    const char* ab = lds + (t & 3) * 16384 + aoff;
    const char* bb = lds + 65536 + (t & 3) * 16384 + boff;
    bf16x8 bfr[4];
#pragma unroll
    for (int n = 0; n < 4; ++n) bfr[n] = *(const bf16x8*)(bb + n * 1024);
    __builtin_amdgcn_s_setprio(1);
#pragma unroll
    for (int m = 0; m < 8; ++m) {
      bf16x8 af = *(const bf16x8*)(ab + m * 1024);
#pragma unroll
      for (int n = 0; n < 4; ++n) acc[m][n] = mfma16(af, bfr[n], acc[m][n]);
    }
    __builtin_amdgcn_s_setprio(0);

    if (t + 2 < NT) {
      asm volatile("s_waitcnt vmcnt(4)" ::: "memory");
      __builtin_amdgcn_s_barrier();
    } else if (t + 2 == NT) {
      asm volatile("s_waitcnt vmcnt(0)" ::: "memory");
      __builtin_amdgcn_s_barrier();
    }
  }
#undef GSTAGE

  const int r0 = bm * 256 + wm * 128 + (l4 << 2);
  const int c0 = bn * 256 + wn * 64 + l15;
  if (!TRANSV) {
#pragma unroll
    for (int m = 0; m < 8; ++m)
#pragma unroll
      for (int n = 0; n < 4; ++n) {
        int r = r0 + m * 16;
        int c = c0 + n * 16;
#pragma unroll
        for (int j = 0; j < 4; ++j)
          C[(size_t)(r + j) * N + c] = f2bf(acc[m][n][j]);
      }
  } else {
#pragma unroll
    for (int m = 0; m < 8; ++m)
#pragma unroll
      for (int n = 0; n < 4; ++n) {
        int ng = c0 + n * 16;
        int h = ng >> 7, d = ng & 127;
        int mg = r0 + m * 16;
        int b = mg >> 11, s = mg & 2047;
        u16x4 pk = { f2bf(acc[m][n][0]), f2bf(acc[m][n][1]),
                     f2bf(acc[m][n][2]), f2bf(acc[m][n][3]) };
        *(u16x4*)(C + ((size_t)((b * Hdim + h) * Ddim + d)) * Sdim + s) = pk;
      }
  }
}

// Causal flash attention, swapped-operand 32x32 MFMA.
// Block = 4 waves sharing one head and a 128-row q-block; each wave owns 32 q
// rows. KV tile = 64, double-buffered in LDS (K swizzled ^row&15, V ^row&7),
// staged via global_load_lds with pre-swizzled global source; 2-phase pipeline
// (stage t+1 issued before compute of t, one __syncthreads per tile).
// Swapped QK^T: sc = mfma(K, Q) -> lane l holds scores of q-row (l&31);
// swapped PV: o = mfma(Vt, P) -> all softmax state per-lane scalar.
__global__ __launch_bounds__(256)
void attn_kernel(const u16* __restrict__ Q, const u16* __restrict__ K,
                 const u16* __restrict__ Vt, float* __restrict__ O) {
  __shared__ u16 Ks[2][64 * 128];
  __shared__ u16 Vs[2][128 * 64];

  const int tid = threadIdx.x;
  const int lane = tid & 63;
  const int w = tid >> 6;
  const int l31 = lane & 31;
  const int hi = lane >> 5;

  const int bid = blockIdx.x;
  const int bh = bid & 63;              // head index b*16+h
  const int qg = 15 - (bid >> 6);       // longest q-groups dispatch first
  const int q0 = qg * 128;
  const int qw0 = q0 + w * 32;          // this wave's 32 q rows
  const int b = bh >> 4, h = bh & 15;

  const u16* Qb = Q + (size_t)b * Sdim * Edim + h * Ddim;
  const u16* Kb = K + (size_t)b * Sdim * Edim + h * Ddim;
  const u16* Vb = Vt + (size_t)bh * Ddim * Sdim;

  // Q fragments (B-operand): lane: q row = qw0+l31, k = c*16 + hi*8 + e
  bf16x8 qf[8];
  {
    const u16* qrow = Qb + (size_t)(qw0 + l31) * Edim + hi * 8;
#pragma unroll
    for (int c = 0; c < 8; ++c) qf[c] = *(const bf16x8*)(qrow + c * 16);
  }

  f32x16 oacc[4];
#pragma unroll
  for (int d = 0; d < 4; ++d)
#pragma unroll
    for (int i = 0; i < 16; ++i) oacc[d][i] = 0.f;

  float m2 = -1e30f, lsum = 0.f;
  const float K1SC = 0.08838834764831845f * 1.4426950408889634f;  // 1/sqrt(128)*log2e
  const int qrel = qw0 + l31;

  const int nt = 2 * qg + 2;                 // block's causal tile count
  const int ntw = (qw0 + 31) / 64 + 1;       // this wave's tile count

  // staging lane constants
  const int krow_off = (lane >> 4);          // K: 4 rows per 1KB issue
  const int kchunk = lane & 15;
  const int vrow_off = (lane >> 3);          // V: 8 rows per 1KB issue
  const int vchunk = lane & 7;

#define STAGE(bufi, tt)                                                        \
  {                                                                            \
    const int kv0s = (tt) * 64;                                                \
    _Pragma("unroll")                                                          \
    for (int i = 0; i < 4; ++i) {                                              \
      const int rbase = w * 16 + i * 4;                                        \
      const int row = rbase + krow_off;                                        \
      const int cs = kchunk ^ (row & 15);                                      \
      load_lds16(Kb + (size_t)(kv0s + row) * Edim + cs * 8,                    \
                 &Ks[bufi][rbase * 128]);                                      \
    }                                                                          \
    _Pragma("unroll")                                                          \
    for (int i = 0; i < 4; ++i) {                                              \
      const int rbase = w * 32 + i * 8;                                        \
      const int row = rbase + vrow_off;                                        \
      const int cs = vchunk ^ (row & 7);                                       \
      load_lds16(Vb + (size_t)row * Sdim + kv0s + cs * 8,                      \
                 &Vs[bufi][rbase * 64]);                                       \
    }                                                                          \
  }

  STAGE(0, 0);
  __syncthreads();

  for (int t = 0; t < nt; ++t) {
    const int cur = t & 1;
    if (t + 1 < nt) STAGE(cur ^ 1, t + 1);

    if (t < ntw) {
      const int kv0 = t * 64;

      // ---- QK^T (swapped): 16 MFMAs, K frags from swizzled LDS ----
      f32x16 sc0, sc1;
#pragma unroll
      for (int i = 0; i < 16; ++i) { sc0[i] = 0.f; sc1[i] = 0.f; }
#pragma unroll
      for (int c = 0; c < 8; ++c) {
        const int ch = c * 2 + hi;
        const int r0r = l31;
        const int r1r = 32 + l31;
        bf16x8 kf0 = *(const bf16x8*)&Ks[cur][r0r * 128 + (ch ^ (r0r & 15)) * 8];
        bf16x8 kf1 = *(const bf16x8*)&Ks[cur][r1r * 128 + (ch ^ (r1r & 15)) * 8];
        sc0 = mfma32(kf0, qf[c], sc0);
        sc1 = mfma32(kf1, qf[c], sc1);
      }

      // ---- scale + causal mask + row max ----
      float psc[32];
      float ma = -1e30f, mb = -1e30f, mc = -1e30f, md = -1e30f;
      if (kv0 + 64 > qw0) {  // diagonal tile: apply mask
#pragma unroll
        for (int r = 0; r < 16; ++r) {
          const int cr = (r & 3) + 8 * (r >> 2) + 4 * hi;
          float v0 = (kv0 + cr <= qrel) ? sc0[r] * K1SC : -1e30f;
          float v1 = (kv0 + 32 + cr <= qrel) ? sc1[r] * K1SC : -1e30f;
          psc[r] = v0; psc[16 + r] = v1;
          if ((r & 3) == 0) { ma = fmaxf(ma, fmaxf(v0, v1)); }
          else if ((r & 3) == 1) { mb = fmaxf(mb, fmaxf(v0, v1)); }
          else if ((r & 3) == 2) { mc = fmaxf(mc, fmaxf(v0, v1)); }
          else { md = fmaxf(md, fmaxf(v0, v1)); }
        }
      } else {
#pragma unroll
        for (int r = 0; r < 16; ++r) {
          float v0 = sc0[r] * K1SC;
          float v1 = sc1[r] * K1SC;
          psc[r] = v0; psc[16 + r] = v1;
          if ((r & 3) == 0) { ma = fmaxf(ma, fmaxf(v0, v1)); }
          else if ((r & 3) == 1) { mb = fmaxf(mb, fmaxf(v0, v1)); }
          else if ((r & 3) == 2) { mc = fmaxf(mc, fmaxf(v0, v1)); }
          else { md = fmaxf(md, fmaxf(v0, v1)); }
        }
      }
      float mt = fmaxf(fmaxf(ma, mb), fmaxf(mc, md));
      float mo = fmaxf(mt, __shfl_xor(mt, 32));

      // ---- defer-max rescale (T13, THR=8 in log2 units) ----
      if (__any(mo - m2 > 8.0f)) {
        float mnew = fmaxf(m2, mo);
        float corr = __builtin_amdgcn_exp2f(m2 - mnew);
        m2 = mnew;
        lsum *= corr;
#pragma unroll
        for (int d = 0; d < 4; ++d)
#pragma unroll
          for (int i = 0; i < 16; ++i) oacc[d][i] *= corr;
      }

      // ---- exp + row sum ----
      float rs0 = 0.f, rs1 = 0.f, rs2 = 0.f, rs3 = 0.f;
#pragma unroll
      for (int r = 0; r < 32; r += 4) {
        psc[r]     = __builtin_amdgcn_exp2f(psc[r] - m2);     rs0 += psc[r];
        psc[r + 1] = __builtin_amdgcn_exp2f(psc[r + 1] - m2); rs1 += psc[r + 1];
        psc[r + 2] = __builtin_amdgcn_exp2f(psc[r + 2] - m2); rs2 += psc[r + 2];
        psc[r + 3] = __builtin_amdgcn_exp2f(psc[r + 3] - m2); rs3 += psc[r + 3];
      }
      float rs = (rs0 + rs1) + (rs2 + rs3);
      rs += __shfl_xor(rs, 32);
      lsum += rs;

      // ---- P -> bf16 fragments (pack + half-swap redistribution) ----
      u32 pk[16], sx[16];
#pragma unroll
      for (int i = 0; i < 16; ++i) pk[i] = pkbf(psc[2 * i], psc[2 * i + 1]);
#pragma unroll
      for (int i = 0; i < 16; ++i) sx[i] = __shfl_xor(pk[i], 32);
      bf16x8 pa[4];
#pragma unroll
      for (int t2 = 0; t2 < 2; ++t2)
#pragma unroll
        for (int q2 = 0; q2 < 2; ++q2) {
          const int base = t2 * 8 + q2 * 4;
          union { u32 w[4]; bf16x8 v; } cv;
          cv.w[0] = hi ? sx[base + 2] : pk[base + 0];
          cv.w[1] = hi ? sx[base + 3] : pk[base + 1];
          cv.w[2] = hi ? pk[base + 2] : sx[base + 0];
          cv.w[3] = hi ? pk[base + 3] : sx[base + 1];
          pa[t2 * 2 + q2] = cv.v;
        }

      // ---- PV (swapped): 16 MFMAs, V frags from swizzled LDS ----
#pragma unroll
      for (int dblk = 0; dblk < 4; ++dblk) {
        const int row = dblk * 32 + l31;
#pragma unroll
        for (int ks = 0; ks < 4; ++ks) {
          const int ch = ks * 2 + hi;
          bf16x8 vf = *(const bf16x8*)&Vs[cur][row * 64 + (ch ^ (row & 7)) * 8];
          oacc[dblk] = mfma32(vf, pa[ks], oacc[dblk]);
        }
      }
    }

    __syncthreads();
  }

  // ---- epilogue: divide by lsum, store f32x4 runs ----
  float inv = 1.0f / lsum;
  float* Ob = O + ((size_t)bh * Sdim + qw0 + l31) * Ddim + hi * 4;
#pragma unroll
  for (int dblk = 0; dblk < 4; ++dblk)
#pragma unroll
    for (int g = 0; g < 4; ++g) {
      f32x4 o4 = { oacc[dblk][4 * g] * inv, oacc[dblk][4 * g + 1] * inv,
                   oacc[dblk][4 * g + 2] * inv, oacc[dblk][4 * g + 3] * inv };
      *(f32x4*)(Ob + dblk * 32 + g * 8) = o4;
    }
}

extern "C" void kernel_launch(void* const* d_in, const int* in_sizes, int n_in,
                              void* d_out, int out_size, void* d_ws, size_t ws_size,
                              hipStream_t stream) {
  const float* x  = (const float*)d_in[0];
  const float* Wq = (const float*)d_in[1];
  const float* Wk = (const float*)d_in[2];
  const float* Wv = (const float*)d_in[3];
  float* out = (float*)d_out;
  char* ws = (char*)d_ws;

  // workspace layout (bytes)
  u16* xb  = (u16*)(ws);                    // 32 MiB  [B*S][E]
  u16* wqb = (u16*)(ws + 33554432ull);      //  8 MiB  [E][E]
  u16* wkb = (u16*)(ws + 41943040ull);
  u16* wvb = (u16*)(ws + 50331648ull);
  u16* Qb  = (u16*)(ws + 58720256ull);      // 32 MiB
  u16* Kb  = (u16*)(ws + 92274688ull);      // 32 MiB
  u16* Vt  = (u16*)(ws + 125829120ull);     // 32 MiB  [B*H][128][S]

  const int nX = Bdim * Sdim * Edim;   // 16777216
  const int nW = Edim * Edim;          // 4194304
  cvt_kernel<<<(nX / 4 + 255) / 256, 256, 0, stream>>>(x, xb, nX / 4);
  cvt_kernel<<<(nW / 4 + 255) / 256, 256, 0, stream>>>(Wq, wqb, nW / 4);
  cvt_kernel<<<(nW / 4 + 255) / 256, 256, 0, stream>>>(Wk, wkb, nW / 4);
  cvt_kernel<<<(nW / 4 + 255) / 256, 256, 0, stream>>>(Wv, wvb, nW / 4);

  dim3 g(Bdim * Sdim / 256, Edim / 256);  // (32, 8)
  gemm_nt<false><<<g, 512, 0, stream>>>(xb, wqb, Qb, Bdim * Sdim, Edim, Edim);
  gemm_nt<false><<<g, 512, 0, stream>>>(xb, wkb, Kb, Bdim * Sdim, Edim, Edim);
  gemm_nt<true ><<<g, 512, 0, stream>>>(xb, wvb, Vt, Bdim * Sdim, Edim, Edim);

  attn_kernel<<<Bdim * Hdim * (Sdim / 128), 256, 0, stream>>>(Qb, Kb, Vt, out);
}

// Round 5
// 374.304 us; speedup vs baseline: 2.5629x; 1.0478x over previous
//
#include <hip/hip_runtime.h>
#include <hip/hip_bf16.h>
#include <stdint.h>

#define Bdim 4
#define Sdim 2048
#define Edim 2048
#define Hdim 16
#define Ddim 128

typedef unsigned short u16;
typedef unsigned int u32;
typedef __attribute__((ext_vector_type(8))) short bf16x8;
typedef __attribute__((ext_vector_type(4))) float f32x4;
typedef __attribute__((ext_vector_type(16))) float f32x16;
typedef __attribute__((ext_vector_type(4))) unsigned short u16x4;
typedef __attribute__((ext_vector_type(2))) unsigned int u32x2;

__device__ inline u16 f2bf(float f) {
  union { float f; uint32_t u; } v; v.f = f;
  uint32_t u = v.u;
  return (u16)((u + 0x7FFFu + ((u >> 16) & 1u)) >> 16);
}

__device__ inline u32 pkbf(float lo, float hi) {
  float2 t; t.x = lo; t.y = hi;
  union { __hip_bfloat162 h2; u32 u; } cv;
  cv.h2 = __float22bfloat162_rn(t);
  return cv.u;
}

__device__ inline f32x4 mfma16(bf16x8 a, bf16x8 b, f32x4 c) {
  return __builtin_amdgcn_mfma_f32_16x16x32_bf16(a, b, c, 0, 0, 0);
}
__device__ inline f32x16 mfma32(bf16x8 a, bf16x8 b, f32x16 c) {
  return __builtin_amdgcn_mfma_f32_32x32x16_bf16(a, b, c, 0, 0, 0);
}

// async global->LDS, 16B per lane; lds dest = wave-uniform base + lane*16
__device__ inline void load_lds16(const void* g, const void* l) {
  __builtin_amdgcn_global_load_lds(
      (__attribute__((address_space(1))) void*)(uintptr_t)g,
      (__attribute__((address_space(3))) void*)(uint32_t)(uintptr_t)l,
      16, 0, 0);
}

__global__ void cvt_kernel(const float* __restrict__ src, u16* __restrict__ dst,
                           int n4, float scale) {
  int i = blockIdx.x * blockDim.x + threadIdx.x;
  if (i < n4) {
    float4 f = ((const float4*)src)[i];
    u16x4 o = { f2bf(f.x * scale), f2bf(f.y * scale),
                f2bf(f.z * scale), f2bf(f.w * scale) };
    ((u16x4*)dst)[i] = o;
  }
}

// C[m][n] = sum_k A[m][k] * Bw[n][k]   (A:[M][K], Bw:[N][K], bf16 in/out)
// 256x256 tile, 8 waves (2M x 4N), BK=32, ring of 4 LDS slots, counted vmcnt,
// one raw s_barrier per K-tile. LDS chunk-swizzle: chunk ^= (row+(row>>2))&3.
// TRANSV: store into Vt[(b*H+h)][d][s] instead of C[m][n].
template <bool TRANSV>
__global__ __launch_bounds__(512, 2)
void gemm_nt(const u16* __restrict__ A, const u16* __restrict__ Bw,
             u16* __restrict__ C, int M, int N, int K) {
  __shared__ char lds[131072];  // [4 slots][A 16KB] then [4 slots][B 16KB]

  const int tid = threadIdx.x;
  const int lane = tid & 63;
  const int w = tid >> 6;            // 0..7
  const int wm = w >> 2, wn = w & 3; // 2 x 4 wave grid
  const int bm = blockIdx.x, bn = blockIdx.y;
  const int NT = K >> 5;             // K-tiles of 32

  // staging lane constants (each 1KB issue = 16 rows x 64B)
  const int srow_off = lane >> 2;    // 0..15
  const int schunk = lane & 3;

  // fragment-read lane constants
  const int l15 = lane & 15;
  const int l4 = lane >> 4;          // k-chunk 0..3
  const int rA = wm * 128 + l15;     // A row base within tile (fm adds 16k, g invariant)
  const int rB = wn * 64 + l15;
  const int gA = (rA + (rA >> 2)) & 3;
  const int gB = (rB + (rB >> 2)) & 3;
  const int aoff = rA * 64 + ((l4 ^ gA) << 4);
  const int boff = rB * 64 + ((l4 ^ gB) << 4);

  const u16* Agp = A + (size_t)(bm * 256) * K;
  const u16* Bgp = Bw + (size_t)(bn * 256) * K;

  f32x4 acc[8][4];
#pragma unroll
  for (int m = 0; m < 8; ++m)
#pragma unroll
    for (int n = 0; n < 4; ++n)
      acc[m][n] = (f32x4){0.f, 0.f, 0.f, 0.f};

#define GSTAGE(tt)                                                             \
  {                                                                            \
    const int slot_ = (tt) & 3;                                                \
    char* ab_ = lds + slot_ * 16384;                                           \
    char* bb_ = lds + 65536 + slot_ * 16384;                                   \
    _Pragma("unroll")                                                          \
    for (int i_ = 0; i_ < 2; ++i_) {                                           \
      const int rbase_ = w * 32 + i_ * 16;                                     \
      const int row_ = rbase_ + srow_off;                                      \
      const int src_ = schunk ^ ((row_ + (row_ >> 2)) & 3);                    \
      load_lds16(Agp + (size_t)row_ * K + (tt) * 32 + src_ * 8,                \
                 ab_ + rbase_ * 64);                                           \
      load_lds16(Bgp + (size_t)row_ * K + (tt) * 32 + src_ * 8,                \
                 bb_ + rbase_ * 64);                                           \
    }                                                                          \
  }

  GSTAGE(0);
  GSTAGE(1);
  asm volatile("s_waitcnt vmcnt(4)" ::: "memory");
  __builtin_amdgcn_s_barrier();

  for (int t = 0; t < NT; ++t) {
    if (t + 2 < NT) GSTAGE(t + 2);

    const char* ab = lds + (t & 3) * 16384 + aoff;
    const char* bb = lds + 65536 + (t & 3) * 16384 + boff;
    bf16x8 bfr[4];
#pragma unroll
    for (int n = 0; n < 4; ++n) bfr[n] = *(const bf16x8*)(bb + n * 1024);
    __builtin_amdgcn_s_setprio(1);
#pragma unroll
    for (int m = 0; m < 8; ++m) {
      bf16x8 af = *(const bf16x8*)(ab + m * 1024);
#pragma unroll
      for (int n = 0; n < 4; ++n) acc[m][n] = mfma16(af, bfr[n], acc[m][n]);
    }
    __builtin_amdgcn_s_setprio(0);

    if (t + 2 < NT) {
      asm volatile("s_waitcnt vmcnt(4)" ::: "memory");
      __builtin_amdgcn_s_barrier();
    } else if (t + 2 == NT) {
      asm volatile("s_waitcnt vmcnt(0)" ::: "memory");
      __builtin_amdgcn_s_barrier();
    }
  }
#undef GSTAGE

  const int r0 = bm * 256 + wm * 128 + (l4 << 2);
  const int c0 = bn * 256 + wn * 64 + l15;
  if (!TRANSV) {
#pragma unroll
    for (int m = 0; m < 8; ++m)
#pragma unroll
      for (int n = 0; n < 4; ++n) {
        int r = r0 + m * 16;
        int c = c0 + n * 16;
#pragma unroll
        for (int j = 0; j < 4; ++j)
          C[(size_t)(r + j) * N + c] = f2bf(acc[m][n][j]);
      }
  } else {
#pragma unroll
    for (int m = 0; m < 8; ++m)
#pragma unroll
      for (int n = 0; n < 4; ++n) {
        int ng = c0 + n * 16;
        int h = ng >> 7, d = ng & 127;
        int mg = r0 + m * 16;
        int b = mg >> 11, s = mg & 2047;
        u16x4 pk = { f2bf(acc[m][n][0]), f2bf(acc[m][n][1]),
                     f2bf(acc[m][n][2]), f2bf(acc[m][n][3]) };
        *(u16x4*)(C + ((size_t)((b * Hdim + h) * Ddim + d)) * Sdim + s) = pk;
      }
  }
}

// Causal flash attention, swapped-operand 32x32 MFMA.
// Block = 4 waves sharing one head and a 128-row q-block; each wave owns 32 q
// rows. KV tile = 64, double-buffered in LDS (K swizzled ^row&15, V ^row&7),
// staged via global_load_lds with pre-swizzled global source; 2-phase pipeline.
// Q is PRE-SCALED by log2e/sqrt(D) (folded into Wq cvt) -> scores in log2
// units, no per-score scale mul. Row sums via ones-MFMA into lacc (only
// lacc[0] is read/rescaled). P redistribution via v_permlane32_swap.
__global__ __launch_bounds__(256)
void attn_kernel(const u16* __restrict__ Q, const u16* __restrict__ K,
                 const u16* __restrict__ Vt, float* __restrict__ O) {
  __shared__ u16 Ks[2][64 * 128];
  __shared__ u16 Vs[2][128 * 64];

  const int tid = threadIdx.x;
  const int lane = tid & 63;
  const int w = tid >> 6;
  const int l31 = lane & 31;
  const int hi = lane >> 5;

  const int bid = blockIdx.x;
  const int bh = bid & 63;              // head index b*16+h
  const int qg = 15 - (bid >> 6);       // longest q-groups dispatch first
  const int q0 = qg * 128;
  const int qw0 = q0 + w * 32;          // this wave's 32 q rows
  const int b = bh >> 4, h = bh & 15;

  const u16* Qb = Q + (size_t)b * Sdim * Edim + h * Ddim;
  const u16* Kb = K + (size_t)b * Sdim * Edim + h * Ddim;
  const u16* Vb = Vt + (size_t)bh * Ddim * Sdim;

  // Q fragments (B-operand): lane: q row = qw0+l31, k = c*16 + hi*8 + e
  bf16x8 qf[8];
  {
    const u16* qrow = Qb + (size_t)(qw0 + l31) * Edim + hi * 8;
#pragma unroll
    for (int c = 0; c < 8; ++c) qf[c] = *(const bf16x8*)(qrow + c * 16);
  }

  f32x16 oacc[4];
#pragma unroll
  for (int d = 0; d < 4; ++d)
#pragma unroll
    for (int i = 0; i < 16; ++i) oacc[d][i] = 0.f;
  f32x16 lacc;
#pragma unroll
  for (int i = 0; i < 16; ++i) lacc[i] = 0.f;

  const short oneb = (short)0x3F80;
  const bf16x8 ones = {oneb, oneb, oneb, oneb, oneb, oneb, oneb, oneb};

  float m2 = -1e30f;
  const int qrel = qw0 + l31;

  const int nt = 2 * qg + 2;                 // block's causal tile count
  const int ntw = (qw0 + 31) / 64 + 1;       // this wave's tile count

  // staging lane constants
  const int krow_off = (lane >> 4);          // K: 4 rows per 1KB issue
  const int kchunk = lane & 15;
  const int vrow_off = (lane >> 3);          // V: 8 rows per 1KB issue
  const int vchunk = lane & 7;

#define STAGE(bufi, tt)                                                        \
  {                                                                            \
    const int kv0s = (tt) * 64;                                                \
    _Pragma("unroll")                                                          \
    for (int i = 0; i < 4; ++i) {                                              \
      const int rbase = w * 16 + i * 4;                                        \
      const int row = rbase + krow_off;                                        \
      const int cs = kchunk ^ (row & 15);                                      \
      load_lds16(Kb + (size_t)(kv0s + row) * Edim + cs * 8,                    \
                 &Ks[bufi][rbase * 128]);                                      \
    }                                                                          \
    _Pragma("unroll")                                                          \
    for (int i = 0; i < 4; ++i) {                                              \
      const int rbase = w * 32 + i * 8;                                        \
      const int row = rbase + vrow_off;                                        \
      const int cs = vchunk ^ (row & 7);                                       \
      load_lds16(Vb + (size_t)row * Sdim + kv0s + cs * 8,                      \
                 &Vs[bufi][rbase * 64]);                                       \
    }                                                                          \
  }

  STAGE(0, 0);
  __syncthreads();

  for (int t = 0; t < nt; ++t) {
    const int cur = t & 1;
    if (t + 1 < nt) STAGE(cur ^ 1, t + 1);

    if (t < ntw) {
      const int kv0 = t * 64;

      // ---- QK^T (swapped): 16 MFMAs, K frags from swizzled LDS ----
      f32x16 sc0, sc1;
#pragma unroll
      for (int i = 0; i < 16; ++i) { sc0[i] = 0.f; sc1[i] = 0.f; }
#pragma unroll
      for (int c = 0; c < 8; ++c) {
        const int ch = c * 2 + hi;
        const int r0r = l31;
        const int r1r = 32 + l31;
        bf16x8 kf0 = *(const bf16x8*)&Ks[cur][r0r * 128 + (ch ^ (r0r & 15)) * 8];
        bf16x8 kf1 = *(const bf16x8*)&Ks[cur][r1r * 128 + (ch ^ (r1r & 15)) * 8];
        sc0 = mfma32(kf0, qf[c], sc0);
        sc1 = mfma32(kf1, qf[c], sc1);
      }

      // ---- causal mask + row max (scores already in log2 units) ----
      float psc[32];
      float ma = -1e30f, mb = -1e30f, mc = -1e30f, md = -1e30f;
      if (kv0 + 64 > qw0) {  // diagonal tile: apply mask
#pragma unroll
        for (int r = 0; r < 16; ++r) {
          const int cr = (r & 3) + 8 * (r >> 2) + 4 * hi;
          float v0 = (kv0 + cr <= qrel) ? sc0[r] : -1e30f;
          float v1 = (kv0 + 32 + cr <= qrel) ? sc1[r] : -1e30f;
          psc[r] = v0; psc[16 + r] = v1;
          if ((r & 3) == 0) { ma = fmaxf(fmaxf(ma, v0), v1); }
          else if ((r & 3) == 1) { mb = fmaxf(fmaxf(mb, v0), v1); }
          else if ((r & 3) == 2) { mc = fmaxf(fmaxf(mc, v0), v1); }
          else { md = fmaxf(fmaxf(md, v0), v1); }
        }
      } else {
#pragma unroll
        for (int r = 0; r < 16; ++r) {
          float v0 = sc0[r];
          float v1 = sc1[r];
          psc[r] = v0; psc[16 + r] = v1;
          if ((r & 3) == 0) { ma = fmaxf(fmaxf(ma, v0), v1); }
          else if ((r & 3) == 1) { mb = fmaxf(fmaxf(mb, v0), v1); }
          else if ((r & 3) == 2) { mc = fmaxf(fmaxf(mc, v0), v1); }
          else { md = fmaxf(fmaxf(md, v0), v1); }
        }
      }
      float mt = fmaxf(fmaxf(ma, mb), fmaxf(mc, md));
      u32x2 mx = __builtin_amdgcn_permlane32_swap(
          __float_as_uint(mt), __float_as_uint(mt), false, false);
      float mo = fmaxf(__uint_as_float(mx.x), __uint_as_float(mx.y));

      // ---- defer-max rescale (T13, THR=8 in log2 units) ----
      if (__any(mo - m2 > 8.0f)) {
        float mnew = fmaxf(m2, mo);
        float corr = __builtin_amdgcn_exp2f(m2 - mnew);
        m2 = mnew;
        lacc[0] *= corr;
#pragma unroll
        for (int d = 0; d < 4; ++d)
#pragma unroll
          for (int i = 0; i < 16; ++i) oacc[d][i] *= corr;
      }

      // ---- exp ----
#pragma unroll
      for (int r = 0; r < 32; ++r)
        psc[r] = __builtin_amdgcn_exp2f(psc[r] - m2);

      // ---- P -> bf16 fragments (pack + permlane32_swap redistribution) ----
      u32 pk[16];
#pragma unroll
      for (int i = 0; i < 16; ++i) pk[i] = pkbf(psc[2 * i], psc[2 * i + 1]);
      bf16x8 pa[4];
#pragma unroll
      for (int t2 = 0; t2 < 2; ++t2)
#pragma unroll
        for (int q2 = 0; q2 < 2; ++q2) {
          const int base = t2 * 8 + q2 * 4;
          u32x2 r0 = __builtin_amdgcn_permlane32_swap(pk[base + 0], pk[base + 2],
                                                      false, false);
          u32x2 r1 = __builtin_amdgcn_permlane32_swap(pk[base + 1], pk[base + 3],
                                                      false, false);
          union { u32 wv[4]; bf16x8 v; } cv;
          cv.wv[0] = r0.x; cv.wv[1] = r1.x; cv.wv[2] = r0.y; cv.wv[3] = r1.y;
          pa[t2 * 2 + q2] = cv.v;
        }

      // ---- PV (swapped): 16 MFMAs + 4 ones-MFMAs (row sums) ----
#pragma unroll
      for (int dblk = 0; dblk < 4; ++dblk) {
        const int row = dblk * 32 + l31;
#pragma unroll
        for (int ks = 0; ks < 4; ++ks) {
          const int ch = ks * 2 + hi;
          bf16x8 vf = *(const bf16x8*)&Vs[cur][row * 64 + (ch ^ (row & 7)) * 8];
          oacc[dblk] = mfma32(vf, pa[ks], oacc[dblk]);
        }
      }
#pragma unroll
      for (int ks = 0; ks < 4; ++ks) lacc = mfma32(ones, pa[ks], lacc);
    }

    __syncthreads();
  }

  // ---- epilogue: divide by row sum, store f32x4 runs ----
  float inv = 1.0f / lacc[0];
  float* Ob = O + ((size_t)bh * Sdim + qw0 + l31) * Ddim + hi * 4;
#pragma unroll
  for (int dblk = 0; dblk < 4; ++dblk)
#pragma unroll
    for (int g = 0; g < 4; ++g) {
      f32x4 o4 = { oacc[dblk][4 * g] * inv, oacc[dblk][4 * g + 1] * inv,
                   oacc[dblk][4 * g + 2] * inv, oacc[dblk][4 * g + 3] * inv };
      *(f32x4*)(Ob + dblk * 32 + g * 8) = o4;
    }
}

extern "C" void kernel_launch(void* const* d_in, const int* in_sizes, int n_in,
                              void* d_out, int out_size, void* d_ws, size_t ws_size,
                              hipStream_t stream) {
  const float* x  = (const float*)d_in[0];
  const float* Wq = (const float*)d_in[1];
  const float* Wk = (const float*)d_in[2];
  const float* Wv = (const float*)d_in[3];
  float* out = (float*)d_out;
  char* ws = (char*)d_ws;

  // workspace layout (bytes)
  u16* xb  = (u16*)(ws);                    // 32 MiB  [B*S][E]
  u16* wqb = (u16*)(ws + 33554432ull);      //  8 MiB  [E][E]
  u16* wkb = (u16*)(ws + 41943040ull);
  u16* wvb = (u16*)(ws + 50331648ull);
  u16* Qb  = (u16*)(ws + 58720256ull);      // 32 MiB
  u16* Kb  = (u16*)(ws + 92274688ull);      // 32 MiB
  u16* Vt  = (u16*)(ws + 125829120ull);     // 32 MiB  [B*H][128][S]

  const int nX = Bdim * Sdim * Edim;   // 16777216
  const int nW = Edim * Edim;          // 4194304
  const float K1SC = 0.08838834764831845f * 1.4426950408889634f;  // log2e/sqrt(D)
  cvt_kernel<<<(nX / 4 + 255) / 256, 256, 0, stream>>>(x, xb, nX / 4, 1.0f);
  cvt_kernel<<<(nW / 4 + 255) / 256, 256, 0, stream>>>(Wq, wqb, nW / 4, K1SC);
  cvt_kernel<<<(nW / 4 + 255) / 256, 256, 0, stream>>>(Wk, wkb, nW / 4, 1.0f);
  cvt_kernel<<<(nW / 4 + 255) / 256, 256, 0, stream>>>(Wv, wvb, nW / 4, 1.0f);

  dim3 g(Bdim * Sdim / 256, Edim / 256);  // (32, 8)
  gemm_nt<false><<<g, 512, 0, stream>>>(xb, wqb, Qb, Bdim * Sdim, Edim, Edim);
  gemm_nt<false><<<g, 512, 0, stream>>>(xb, wkb, Kb, Bdim * Sdim, Edim, Edim);
  gemm_nt<true ><<<g, 512, 0, stream>>>(xb, wvb, Vt, Bdim * Sdim, Edim, Edim);

  attn_kernel<<<Bdim * Hdim * (Sdim / 128), 256, 0, stream>>>(Qb, Kb, Vt, out);
}